// Round 1
// 434.638 us; speedup vs baseline: 1.0221x; 1.0221x over previous
//
#include <hip/hip_runtime.h>

#define USH unsigned short

// ---------- bf16 helpers (storage = unsigned short) ----------
__device__ __forceinline__ float b2f(USH u) {
    union { unsigned int i; float f; } x; x.i = ((unsigned int)u) << 16; return x.f;
}
__device__ __forceinline__ USH f2b(float f) {
    union { float f; unsigned int i; } x; x.f = f;
    unsigned int r = x.i + (0x7fffu + ((x.i >> 16) & 1u));  // RNE
    return (USH)(r >> 16);
}
__device__ __forceinline__ float ldf(const USH* p)  { return b2f(*p); }
__device__ __forceinline__ float ldf(const float* p){ return *p; }
__device__ __forceinline__ void stf(USH* p, float v)  { *p = f2b(v); }
__device__ __forceinline__ void stf(float* p, float v){ *p = v; }

// async global->LDS, 16B per lane (dest = wave-uniform base + lane*16)
#define GLOAD16(gp, lp) __builtin_amdgcn_global_load_lds(                     \
    (const __attribute__((address_space(1))) void*)(gp),                      \
    (__attribute__((address_space(3))) void*)(lp), 16, 0, 0)

typedef __attribute__((ext_vector_type(8))) __bf16 bf16x8;
typedef __attribute__((ext_vector_type(4))) float  floatx4;

// =====================================================================
// Weight transpose+convert: W[K][N] f32 -> WT[N][K] bf16.
// =====================================================================
__global__ __launch_bounds__(256) void transpose_f2b(const float* __restrict__ W,
                                                     USH* __restrict__ WT,
                                                     int K, int N) {
    __shared__ USH t[64][72];
    int n0 = blockIdx.x * 64, k0 = blockIdx.y * 64;
    int tid = threadIdx.x;
    int kr = tid >> 4, nc = (tid & 15) * 4;
#pragma unroll
    for (int r = 0; r < 4; r++) {
        int k = kr + r * 16;
        float4 v = *(const float4*)(W + (size_t)(k0 + k) * N + n0 + nc);
        t[nc + 0][k] = f2b(v.x); t[nc + 1][k] = f2b(v.y);
        t[nc + 2][k] = f2b(v.z); t[nc + 3][k] = f2b(v.w);
    }
    __syncthreads();
    int nr = tid >> 2, kc = (tid & 3) * 8;
#pragma unroll
    for (int r = 0; r < 2; r++) {
        int k = kc + r * 32;
        *(int4*)(WT + (size_t)(n0 + nr) * K + k0 + k) = *(const int4*)&t[nr][k];
    }
}

// =====================================================================
// LayerNorm rows of 1024. block=256, one block/row.
// =====================================================================
template <typename TX>
__global__ __launch_bounds__(256) void ln_rows(const TX* __restrict__ x,
                                               const float* __restrict__ g,
                                               const float* __restrict__ bb,
                                               USH* __restrict__ y) {
    int row = blockIdx.x, tid = threadIdx.x;
    const TX* xr = x + (size_t)row * 1024 + tid * 4;
    float v[4];
#pragma unroll
    for (int i = 0; i < 4; i++) v[i] = ldf(xr + i);
    float s  = v[0] + v[1] + v[2] + v[3];
    float ss = v[0]*v[0] + v[1]*v[1] + v[2]*v[2] + v[3]*v[3];
#pragma unroll
    for (int o = 32; o; o >>= 1) { s += __shfl_down(s, o); ss += __shfl_down(ss, o); }
    __shared__ float red[10];
    int w = tid >> 6;
    if ((tid & 63) == 0) { red[w] = s; red[4 + w] = ss; }
    __syncthreads();
    if (tid == 0) {
        float S = red[0] + red[1] + red[2] + red[3];
        float SS = red[4] + red[5] + red[6] + red[7];
        float mean = S * (1.f / 1024.f);
        float var  = SS * (1.f / 1024.f) - mean * mean;
        red[8] = mean; red[9] = rsqrtf(var + 1e-5f);
    }
    __syncthreads();
    float mean = red[8], rstd = red[9];
    USH* yr = y + (size_t)row * 1024 + tid * 4;
#pragma unroll
    for (int i = 0; i < 4; i++) {
        int c = tid * 4 + i;
        yr[i] = f2b((v[i] - mean) * rstd * g[c] + bb[c]);
    }
}

// =====================================================================
// zh = z @ wca + bca, emitting packed MFMA operand rows (head-major),
// exp2-domain fold (gvl = softplus(gamma)*log2e):
//  zq_pack[h][row][32]: [ 2*gvl*s (16)], [16]=-gvl*ks, [17]=[18]=-gvl, 0..
//  zk_pack[h][row][32]: [ f2b(s) (16)],  [16]=1.0, [17]=ks_hi, [18]=ks_lo, 0..
// so mfma(zq_row, zk_row) = -gvl*(qs + ks - 2 q.k) <= 0 (log2 units),
// and p = exp2(sacc) is a single v_exp_f32.
// =====================================================================
__global__ __launch_bounds__(256) void zh_kernel(const float* __restrict__ z,
                                                 const float* __restrict__ wca,
                                                 const float* __restrict__ bca,
                                                 const float* __restrict__ gamma,
                                                 USH* __restrict__ zq_pack,
                                                 USH* __restrict__ zk_pack) {
    int row = blockIdx.x, n = threadIdx.x;
    __shared__ float zrow[64];
    if (n < 64) zrow[n] = z[(size_t)row * 64 + n];
    __syncthreads();
    float s = bca[n];
#pragma unroll 8
    for (int k = 0; k < 64; k++) s = fmaf(zrow[k], wca[(size_t)k * 256 + n], s);
    int h = n >> 4, c = n & 15;
    float gvl = log1pf(__expf(gamma[h])) * 1.44269504f;  // softplus * log2e
    USH u = f2b(s);
    float sv = b2f(u);
    float sq = sv * sv;
    sq += __shfl_xor(sq, 1); sq += __shfl_xor(sq, 2);
    sq += __shfl_xor(sq, 4); sq += __shfl_xor(sq, 8);
    size_t base = ((size_t)h * 4096 + row) * 32;
    zk_pack[base + c] = u;
    zq_pack[base + c] = f2b(2.f * gvl * s);
    if (c == 0) {
        USH hi = f2b(sq);
        float lo = sq - b2f(hi);
        unsigned int kw0 = 0x3F80u | ((unsigned int)hi << 16);
        unsigned int kw1 = (unsigned int)f2b(lo);
        uint4 kv = {kw0, kw1, 0u, 0u};
        uint4 zz = {0u, 0u, 0u, 0u};
        *(uint4*)(zk_pack + base + 16) = kv;
        *(uint4*)(zk_pack + base + 24) = zz;
        unsigned int qw0 = (unsigned int)f2b(-gvl * sq) | ((unsigned int)f2b(-gvl) << 16);
        unsigned int qw1 = (unsigned int)f2b(-gvl);
        uint4 qv = {qw0, qw1, 0u, 0u};
        *(uint4*)(zq_pack + base + 16) = qv;
        *(uint4*)(zq_pack + base + 24) = zz;
    }
}

// =====================================================================
// z_next = hn(bf16 ws) @ wcn(f32) + bcn  (4096 rows, K=1024, N=64) -> f32
// =====================================================================
__global__ __launch_bounds__(256) void znext_kernel(const USH* __restrict__ hn,
                                                    const float* __restrict__ wcn,
                                                    const float* __restrict__ bcn,
                                                    float* __restrict__ zn) {
    int row = blockIdx.x, t = threadIdx.x;
    int n = t & 63, ks = t >> 6;
    const USH* a = hn + (size_t)row * 1024 + ks * 256;
    const float* w = wcn + (size_t)ks * 256 * 64 + n;
    float s = 0.f;
#pragma unroll 4
    for (int k = 0; k < 256; k++) s = fmaf(b2f(a[k]), w[(size_t)k * 64], s);
    __shared__ float part[4][64];
    part[ks][n] = s;
    __syncthreads();
    if (t < 64)
        zn[(size_t)row * 64 + t] = part[0][t] + part[1][t] + part[2][t] + part[3][t] + bcn[t];
}

// =====================================================================
// MFMA GEMM v4: BK=64, XOR-swizzled global_load_lds staging.
// Tile (MI*32) x (NI*32); 4 waves in 2x2; XCD-affine grid (x = m-block).
// MI=NI=2 -> 64x64 tile, 16KB LDS, 4 blocks/CU at 1024-block grids.
// EPI: 0 = plain | 1 = +res | 2 = gelu | 3 = +res
// =====================================================================
template <int EPI, int MI, int NI, typename TRES, typename TOUT>
__global__ __launch_bounds__(256) void gemm_kernel(const USH* __restrict__ A,
                                                   const USH* __restrict__ WT,
                                                   const float* __restrict__ bias,
                                                   const TRES* __restrict__ res,
                                                   TOUT* __restrict__ out,
                                                   int M, int N, int K) {
    constexpr int BM = MI * 32;
    constexpr int BN = NI * 32;
    __shared__ __align__(16) USH lA[BM][64];
    __shared__ __align__(16) USH lB[BN][64];
    int tid = threadIdx.x;
    int lane = tid & 63, wave = tid >> 6;
    int wr = wave >> 1, wc = wave & 1;
    int quad = lane >> 4, l15 = lane & 15;
    int m0 = blockIdx.x * BM, n0 = blockIdx.y * BN;

    int srow = tid >> 3;                 // 0..31 (rows per 4KB chunk)
    int k8   = tid & 7;                  // 16B granule within row
    int scol = (k8 ^ (srow & 7)) * 8;    // swizzled source column

    const USH* gA = A + (size_t)(m0 + srow) * K + scol;
    const USH* gB = WT + (size_t)(n0 + srow) * K + scol;
    USH* lA0 = &lA[0][0] + tid * 8;      // lane*16B dest
    USH* lB0 = &lB[0][0] + tid * 8;
    int xo = (l15 & 7) * 8;              // read-side XOR

    floatx4 acc[MI][NI] = {};

    for (int k0 = 0; k0 < K; k0 += 64) {
#pragma unroll
        for (int c = 0; c < MI; c++)
            GLOAD16(gA + (size_t)c * 32 * K + k0, lA0 + c * 2048);
#pragma unroll
        for (int c = 0; c < NI; c++)
            GLOAD16(gB + (size_t)c * 32 * K + k0, lB0 + c * 2048);
        __syncthreads();

#pragma unroll
        for (int ks = 0; ks < 2; ks++) {
            bf16x8 bfr[NI];
#pragma unroll
            for (int ni = 0; ni < NI; ni++)
                bfr[ni] = *(const bf16x8*)&lB[wc * (NI * 16) + ni * 16 + l15][(ks * 32 + quad * 8) ^ xo];
#pragma unroll
            for (int mi = 0; mi < MI; mi++) {
                bf16x8 afr = *(const bf16x8*)&lA[wr * (MI * 16) + mi * 16 + l15][(ks * 32 + quad * 8) ^ xo];
#pragma unroll
                for (int ni = 0; ni < NI; ni++)
                    acc[mi][ni] = __builtin_amdgcn_mfma_f32_16x16x32_bf16(afr, bfr[ni], acc[mi][ni], 0, 0, 0);
            }
        }
        __syncthreads();
    }

    float bias_v[NI];
#pragma unroll
    for (int ni = 0; ni < NI; ni++) bias_v[ni] = bias[n0 + wc * (NI * 16) + ni * 16 + l15];

#pragma unroll
    for (int mi = 0; mi < MI; mi++) {
#pragma unroll
        for (int r = 0; r < 4; r++) {
            int row = m0 + wr * (MI * 16) + mi * 16 + quad * 4 + r;
            size_t base = (size_t)row * N;
#pragma unroll
            for (int ni = 0; ni < NI; ni++) {
                int col = n0 + wc * (NI * 16) + ni * 16 + l15;
                float v = acc[mi][ni][r] + bias_v[ni];
                if (EPI == 2) v = 0.5f * v * (1.f + erff(v * 0.70710678118f));
                if (EPI == 1 || EPI == 3) v += ldf(res + base + col);
                stf(out + base + col, v);
            }
        }
    }
}

// =====================================================================
// Flash distance-attention v7: exp2-domain fold, MFMA rowsum.
// v7: 512 threads / 8 waves per block (was 256/4). Grid is fixed at 512
// blocks (= 2 blocks/CU exactly), which capped occupancy at 8 waves/CU
// (21% measured, latency-bound: MfmaUtil 16%, VALUBusy 44%, HBM 2.8%).
// 8 waves x 16 q-rows doubles resident waves/SIMD (2->4) at identical
// LDS footprint (43008 B: Pb [4][32][72] -> [8][16][72]) and identical
// LDS access patterns. Staging split: waves 0-3 build VbT (interleave),
// waves 4-7 stage KbT.
// =====================================================================
__global__ __launch_bounds__(512) void attn6_kernel(const USH* __restrict__ zq_pack,
                                                    const USH* __restrict__ zk_pack,
                                                    const USH* __restrict__ value,
                                                    USH* __restrict__ attn_out) {
    int b = blockIdx.x >> 4, h = blockIdx.x & 15;
    int q0 = blockIdx.y * 128;
    int tid = threadIdx.x, lane = tid & 63, wq = tid >> 6;   // wq 0..7
    int quad = lane >> 4, l15 = lane & 15;

    __shared__ __align__(16) USH Qb[128][40];
    __shared__ __align__(16) USH KbT[64][40];
    __shared__ __align__(16) USH VbT[64][72];
    __shared__ __align__(16) USH Pb[8][16][72];

    const size_t zrow0 = (size_t)b * 2048;
    const USH* zq = zq_pack + ((size_t)h * 4096 + zrow0) * 32;
    const USH* zk = zk_pack + ((size_t)h * 4096 + zrow0) * 32;
    const size_t vbase = zrow0 * 1024 + h * 64;

    {
        // 512 threads load 128 rows x 32 cols (8 USH each)
        int row = tid >> 2, c0 = (tid & 3) * 8;
        *(uint4*)&Qb[row][c0] = *(const uint4*)(zq + (size_t)(q0 + row) * 32 + c0);
    }
    __syncthreads();

    bf16x8 afragQ = *(const bf16x8*)&Qb[wq * 16 + l15][quad * 8];

    // ones fragment (bf16 1.0 x8)
    union { unsigned int u[4]; bf16x8 v; } onesu;
#pragma unroll
    for (int i = 0; i < 4; i++) onesu.u[i] = 0x3F803F80u;
    bf16x8 ones = onesu.v;

    floatx4 oacc[4] = {};
    floatx4 lacc = {};

    for (int kt = 0; kt < 2048; kt += 64) {
        __syncthreads();
        if (tid < 256) {
            // waves 0-3: VbT interleaved transpose (2 keys x 8 dh per thread)
            int key2 = (tid & 31) * 2;
            int dh0 = (tid >> 5) * 8;
            const USH* s0 = value + vbase + (size_t)(kt + key2) * 1024 + dh0;
            int4 ta = *(const int4*)s0;
            int4 tb = *(const int4*)(s0 + 1024);
            const USH* ua = (const USH*)&ta;
            const USH* ub = (const USH*)&tb;
#pragma unroll
            for (int e = 0; e < 8; e++) {
                unsigned int dw = (unsigned int)ua[e] | ((unsigned int)ub[e] << 16);
                *(unsigned int*)&VbT[dh0 + e][key2] = dw;
            }
        } else {
            // waves 4-7: KbT rows (16B per thread)
            int t = tid - 256;
            int row = t >> 2, c0 = (t & 3) * 8;
            *(uint4*)&KbT[row][c0] = *(const uint4*)(zk + (size_t)(kt + row) * 32 + c0);
        }
        __syncthreads();

        bf16x8 bk[4];
#pragma unroll
        for (int ni = 0; ni < 4; ni++)
            bk[ni] = *(const bf16x8*)&KbT[ni * 16 + l15][quad * 8];

        floatx4 sacc[4];
#pragma unroll
        for (int ni = 0; ni < 4; ni++) {
            floatx4 zz = {};
            sacc[ni] = __builtin_amdgcn_mfma_f32_16x16x32_bf16(afragQ, bk[ni], zz, 0, 0, 0);
        }
#pragma unroll
        for (int r = 0; r < 4; r++) {
#pragma unroll
            for (int ni = 0; ni < 4; ni++) {
                float pf = exp2f(sacc[ni][r]);   // single v_exp_f32
                union { float f; unsigned int i; } cv; cv.f = pf;
                Pb[wq][quad * 4 + r][ni * 16 + l15] = (USH)(cv.i >> 16);
            }
        }

        // ---- PV + rowsum (Pb wave-private; same-wave LDS in-order) ----
#pragma unroll
        for (int ks2 = 0; ks2 < 2; ks2++) {
            bf16x8 bv[4];
#pragma unroll
            for (int nd = 0; nd < 4; nd++)
                bv[nd] = *(const bf16x8*)&VbT[nd * 16 + l15][ks2 * 32 + quad * 8];
            bf16x8 ap = *(const bf16x8*)&Pb[wq][l15][ks2 * 32 + quad * 8];
#pragma unroll
            for (int nd = 0; nd < 4; nd++)
                oacc[nd] = __builtin_amdgcn_mfma_f32_16x16x32_bf16(ap, bv[nd], oacc[nd], 0, 0, 0);
            lacc = __builtin_amdgcn_mfma_f32_16x16x32_bf16(ap, ones, lacc, 0, 0, 0);
        }
    }

    // ---- epilogue: lacc holds the rowsum in every column ----
#pragma unroll
    for (int r = 0; r < 4; r++) {
        float inv = 1.f / lacc[r];
        int row = q0 + wq * 16 + quad * 4 + r;
        USH* o = attn_out + (zrow0 + row) * 1024 + h * 64;
#pragma unroll
        for (int nd = 0; nd < 4; nd++) o[nd * 16 + l15] = f2b(oacc[nd][r] * inv);
    }
}

// =====================================================================
// z_out = LN(z + z_next) over rows of 64. block = 64 (one wave) per row.
// =====================================================================
__global__ __launch_bounds__(64) void lnc_kernel(const float* __restrict__ z,
                                                 const float* __restrict__ zn,
                                                 const float* __restrict__ g,
                                                 const float* __restrict__ bb,
                                                 float* __restrict__ out) {
    int row = blockIdx.x, t = threadIdx.x;
    float v = z[(size_t)row * 64 + t] + zn[(size_t)row * 64 + t];
    float s = v, ss = v * v;
#pragma unroll
    for (int o = 32; o; o >>= 1) { s += __shfl_xor(s, o); ss += __shfl_xor(ss, o); }
    float mean = s * (1.f / 64.f);
    float rstd = rsqrtf(ss * (1.f / 64.f) - mean * mean + 1e-5f);
    out[(size_t)row * 64 + t] = (v - mean) * rstd * g[t] + bb[t];
}

// =====================================================================
extern "C" void kernel_launch(void* const* d_in, const int* in_sizes, int n_in,
                              void* d_out, int out_size, void* d_ws, size_t ws_size,
                              hipStream_t stream) {
    // workspace layout (61 MB):
    //   [0,8M)    value    [8,16M) attn_o    [16,20M) zq_pack
    //   [20,24M)  zk_pack  [24,32M) hn
    //   [0,32M)   mid (overlays, written step 8)
    //   [32,40M)  hn2   [40,41M) znext
    //   [41,43M)  wvT  [43,45M) woT  [45,53M) w1T  [53,61M) w2T
    // h1 (f32) lives in d_out's h region.
    char* p = (char*)d_ws;
    USH*   value   = (USH*)(p);
    USH*   attn_o  = (USH*)(p + ((size_t)8  << 20));
    USH*   zq_pack = (USH*)(p + ((size_t)16 << 20));
    USH*   zk_pack = (USH*)(p + ((size_t)20 << 20));
    USH*   hn      = (USH*)(p + ((size_t)24 << 20));
    USH*   mid     = (USH*)(p);
    USH*   hn2     = (USH*)(p + ((size_t)32 << 20));
    float* znext   = (float*)(p + ((size_t)40 << 20));
    USH*   wvT     = (USH*)(p + ((size_t)41 << 20));
    USH*   woT     = (USH*)(p + ((size_t)43 << 20));
    USH*   w1T     = (USH*)(p + ((size_t)45 << 20));
    USH*   w2T     = (USH*)(p + ((size_t)53 << 20));

    const float *h    = (const float*)d_in[0],  *z    = (const float*)d_in[1];
    const float *wv   = (const float*)d_in[2],  *bv   = (const float*)d_in[3];
    const float *wca  = (const float*)d_in[4],  *bca  = (const float*)d_in[5];
    const float *wcn  = (const float*)d_in[6],  *bcn  = (const float*)d_in[7];
    const float *wo   = (const float*)d_in[8],  *bo   = (const float*)d_in[9];
    const float *gam  = (const float*)d_in[10];
    const float *w1   = (const float*)d_in[11], *b1   = (const float*)d_in[12];
    const float *w2   = (const float*)d_in[13], *b2   = (const float*)d_in[14];
    const float *ln1g = (const float*)d_in[15], *ln1b = (const float*)d_in[16];
    const float *ln2g = (const float*)d_in[17], *ln2b = (const float*)d_in[18];
    const float *lncg = (const float*)d_in[19], *lncb = (const float*)d_in[20];

    float* out_h = (float*)d_out;
    float* out_z = out_h + (size_t)4096 * 1024;
    float* h1    = out_h;

    // 0. weight conversion (f32 [K][N] -> bf16 [N][K])
    transpose_f2b<<<dim3(16, 16), 256, 0, stream>>>(wv, wvT, 1024, 1024);
    transpose_f2b<<<dim3(16, 16), 256, 0, stream>>>(wo, woT, 1024, 1024);
    transpose_f2b<<<dim3(64, 16), 256, 0, stream>>>(w1, w1T, 1024, 4096);
    transpose_f2b<<<dim3(16, 64), 256, 0, stream>>>(w2, w2T, 4096, 1024);

    // 1. hn = LN1(h)
    ln_rows<float><<<4096, 256, 0, stream>>>(h, ln1g, ln1b, hn);
    // 2. packed attention operands from z (exp2-domain)
    zh_kernel<<<4096, 256, 0, stream>>>(z, wca, bca, gam, zq_pack, zk_pack);
    // 3. value = hn @ wv + bv           (64x64 tiles, 1024 blocks)
    gemm_kernel<0, 2, 2, USH, USH><<<dim3(64, 16), 256, 0, stream>>>(hn, wvT, bv, (const USH*)nullptr, value, 4096, 1024, 1024);
    // 4. z_next = hn @ wcn + bcn
    znext_kernel<<<4096, 256, 0, stream>>>(hn, wcn, bcn, znext);
    // 5. attention (MFMA flash, exp2-fold, MFMA rowsum) — 512 thr / 8 waves
    attn6_kernel<<<dim3(32, 16), 512, 0, stream>>>(zq_pack, zk_pack, value, attn_o);
    // 6. h1 = h + attn_o @ wo + bo      (out f32 -> d_out h-region)
    gemm_kernel<1, 2, 2, float, float><<<dim3(64, 16), 256, 0, stream>>>(attn_o, woT, bo, h, h1, 4096, 1024, 1024);
    // 7. hn2 = LN2(h1)
    ln_rows<float><<<4096, 256, 0, stream>>>(h1, ln2g, ln2b, hn2);
    // 8. mid = gelu(hn2 @ w1 + b1)      (128x128 tiles, 1024 blocks)
    gemm_kernel<2, 4, 4, USH, USH><<<dim3(32, 32), 256, 0, stream>>>(hn2, w1T, b1, (const USH*)nullptr, mid, 4096, 4096, 1024);
    // 9. out_h = h1 + mid @ w2 + b2     (res==out same-thread, safe)
    gemm_kernel<3, 2, 2, float, float><<<dim3(64, 16), 256, 0, stream>>>(mid, w2T, b2, h1, out_h, 4096, 1024, 4096);
    // 10. out_z = LN(z + znext)
    lnc_kernel<<<4096, 64, 0, stream>>>(z, znext, lncg, lncb, out_z);
}

// Round 2
// 397.127 us; speedup vs baseline: 1.1187x; 1.0945x over previous
//
#include <hip/hip_runtime.h>

#define USH unsigned short

// ---------- bf16 helpers (storage = unsigned short) ----------
__device__ __forceinline__ float b2f(USH u) {
    union { unsigned int i; float f; } x; x.i = ((unsigned int)u) << 16; return x.f;
}
__device__ __forceinline__ USH f2b(float f) {
    union { float f; unsigned int i; } x; x.f = f;
    unsigned int r = x.i + (0x7fffu + ((x.i >> 16) & 1u));  // RNE
    return (USH)(r >> 16);
}
__device__ __forceinline__ float ldf(const USH* p)  { return b2f(*p); }
__device__ __forceinline__ float ldf(const float* p){ return *p; }
__device__ __forceinline__ void stf(USH* p, float v)  { *p = f2b(v); }
__device__ __forceinline__ void stf(float* p, float v){ *p = v; }

// async global->LDS, 16B per lane (dest = wave-uniform base + lane*16)
#define GLOAD16(gp, lp) __builtin_amdgcn_global_load_lds(                     \
    (const __attribute__((address_space(1))) void*)(gp),                      \
    (__attribute__((address_space(3))) void*)(lp), 16, 0, 0)

typedef __attribute__((ext_vector_type(8))) __bf16 bf16x8;
typedef __attribute__((ext_vector_type(4))) float  floatx4;

// =====================================================================
// Weight transpose+convert: W[K][N] f32 -> WT[N][K] bf16.
// =====================================================================
__global__ __launch_bounds__(256) void transpose_f2b(const float* __restrict__ W,
                                                     USH* __restrict__ WT,
                                                     int K, int N) {
    __shared__ USH t[64][72];
    int n0 = blockIdx.x * 64, k0 = blockIdx.y * 64;
    int tid = threadIdx.x;
    int kr = tid >> 4, nc = (tid & 15) * 4;
#pragma unroll
    for (int r = 0; r < 4; r++) {
        int k = kr + r * 16;
        float4 v = *(const float4*)(W + (size_t)(k0 + k) * N + n0 + nc);
        t[nc + 0][k] = f2b(v.x); t[nc + 1][k] = f2b(v.y);
        t[nc + 2][k] = f2b(v.z); t[nc + 3][k] = f2b(v.w);
    }
    __syncthreads();
    int nr = tid >> 2, kc = (tid & 3) * 8;
#pragma unroll
    for (int r = 0; r < 2; r++) {
        int k = kc + r * 32;
        *(int4*)(WT + (size_t)(n0 + nr) * K + k0 + k) = *(const int4*)&t[nr][k];
    }
}

// =====================================================================
// LayerNorm rows of 1024. block=256, one block/row.
// =====================================================================
template <typename TX>
__global__ __launch_bounds__(256) void ln_rows(const TX* __restrict__ x,
                                               const float* __restrict__ g,
                                               const float* __restrict__ bb,
                                               USH* __restrict__ y) {
    int row = blockIdx.x, tid = threadIdx.x;
    const TX* xr = x + (size_t)row * 1024 + tid * 4;
    float v[4];
#pragma unroll
    for (int i = 0; i < 4; i++) v[i] = ldf(xr + i);
    float s  = v[0] + v[1] + v[2] + v[3];
    float ss = v[0]*v[0] + v[1]*v[1] + v[2]*v[2] + v[3]*v[3];
#pragma unroll
    for (int o = 32; o; o >>= 1) { s += __shfl_down(s, o); ss += __shfl_down(ss, o); }
    __shared__ float red[10];
    int w = tid >> 6;
    if ((tid & 63) == 0) { red[w] = s; red[4 + w] = ss; }
    __syncthreads();
    if (tid == 0) {
        float S = red[0] + red[1] + red[2] + red[3];
        float SS = red[4] + red[5] + red[6] + red[7];
        float mean = S * (1.f / 1024.f);
        float var  = SS * (1.f / 1024.f) - mean * mean;
        red[8] = mean; red[9] = rsqrtf(var + 1e-5f);
    }
    __syncthreads();
    float mean = red[8], rstd = red[9];
    USH* yr = y + (size_t)row * 1024 + tid * 4;
#pragma unroll
    for (int i = 0; i < 4; i++) {
        int c = tid * 4 + i;
        yr[i] = f2b((v[i] - mean) * rstd * g[c] + bb[c]);
    }
}

// =====================================================================
// zh = z @ wca + bca, emitting packed MFMA operand rows (head-major),
// exp2-domain fold (gvl = softplus(gamma)*log2e):
//  zq_pack[h][row][32]: [ 2*gvl*s (16)], [16]=-gvl*ks, [17]=[18]=-gvl, 0..
//  zk_pack[h][row][32]: [ f2b(s) (16)],  [16]=1.0, [17]=ks_hi, [18]=ks_lo, 0..
// so mfma(zq_row, zk_row) = -gvl*(qs + ks - 2 q.k) <= 0 (log2 units),
// and p = exp2(sacc) is a single v_exp_f32.
// =====================================================================
__global__ __launch_bounds__(256) void zh_kernel(const float* __restrict__ z,
                                                 const float* __restrict__ wca,
                                                 const float* __restrict__ bca,
                                                 const float* __restrict__ gamma,
                                                 USH* __restrict__ zq_pack,
                                                 USH* __restrict__ zk_pack) {
    int row = blockIdx.x, n = threadIdx.x;
    __shared__ float zrow[64];
    if (n < 64) zrow[n] = z[(size_t)row * 64 + n];
    __syncthreads();
    float s = bca[n];
#pragma unroll 8
    for (int k = 0; k < 64; k++) s = fmaf(zrow[k], wca[(size_t)k * 256 + n], s);
    int h = n >> 4, c = n & 15;
    float gvl = log1pf(__expf(gamma[h])) * 1.44269504f;  // softplus * log2e
    USH u = f2b(s);
    float sv = b2f(u);
    float sq = sv * sv;
    sq += __shfl_xor(sq, 1); sq += __shfl_xor(sq, 2);
    sq += __shfl_xor(sq, 4); sq += __shfl_xor(sq, 8);
    size_t base = ((size_t)h * 4096 + row) * 32;
    zk_pack[base + c] = u;
    zq_pack[base + c] = f2b(2.f * gvl * s);
    if (c == 0) {
        USH hi = f2b(sq);
        float lo = sq - b2f(hi);
        unsigned int kw0 = 0x3F80u | ((unsigned int)hi << 16);
        unsigned int kw1 = (unsigned int)f2b(lo);
        uint4 kv = {kw0, kw1, 0u, 0u};
        uint4 zz = {0u, 0u, 0u, 0u};
        *(uint4*)(zk_pack + base + 16) = kv;
        *(uint4*)(zk_pack + base + 24) = zz;
        unsigned int qw0 = (unsigned int)f2b(-gvl * sq) | ((unsigned int)f2b(-gvl) << 16);
        unsigned int qw1 = (unsigned int)f2b(-gvl);
        uint4 qv = {qw0, qw1, 0u, 0u};
        *(uint4*)(zq_pack + base + 16) = qv;
        *(uint4*)(zq_pack + base + 24) = zz;
    }
}

// =====================================================================
// MFMA GEMM v4: BK=64, XOR-swizzled global_load_lds staging.
// Tile (MI*32) x (NI*32); 4 waves in 2x2; XCD-affine grid (x = m-block).
// MI=NI=2 -> 64x64 tile, 16KB LDS, 4 blocks/CU at 1024-block grids.
// MI=NI=1 -> 32x32 tile (used for the skinny z_next GEMM, N=64).
// EPI: 0 = plain | 1 = +res | 2 = gelu | 3 = +res
// =====================================================================
template <int EPI, int MI, int NI, typename TRES, typename TOUT>
__global__ __launch_bounds__(256) void gemm_kernel(const USH* __restrict__ A,
                                                   const USH* __restrict__ WT,
                                                   const float* __restrict__ bias,
                                                   const TRES* __restrict__ res,
                                                   TOUT* __restrict__ out,
                                                   int M, int N, int K) {
    constexpr int BM = MI * 32;
    constexpr int BN = NI * 32;
    __shared__ __align__(16) USH lA[BM][64];
    __shared__ __align__(16) USH lB[BN][64];
    int tid = threadIdx.x;
    int lane = tid & 63, wave = tid >> 6;
    int wr = wave >> 1, wc = wave & 1;
    int quad = lane >> 4, l15 = lane & 15;
    int m0 = blockIdx.x * BM, n0 = blockIdx.y * BN;

    int srow = tid >> 3;                 // 0..31 (rows per 4KB chunk)
    int k8   = tid & 7;                  // 16B granule within row
    int scol = (k8 ^ (srow & 7)) * 8;    // swizzled source column

    const USH* gA = A + (size_t)(m0 + srow) * K + scol;
    const USH* gB = WT + (size_t)(n0 + srow) * K + scol;
    USH* lA0 = &lA[0][0] + tid * 8;      // lane*16B dest
    USH* lB0 = &lB[0][0] + tid * 8;
    int xo = (l15 & 7) * 8;              // read-side XOR

    floatx4 acc[MI][NI] = {};

    for (int k0 = 0; k0 < K; k0 += 64) {
#pragma unroll
        for (int c = 0; c < MI; c++)
            GLOAD16(gA + (size_t)c * 32 * K + k0, lA0 + c * 2048);
#pragma unroll
        for (int c = 0; c < NI; c++)
            GLOAD16(gB + (size_t)c * 32 * K + k0, lB0 + c * 2048);
        __syncthreads();

#pragma unroll
        for (int ks = 0; ks < 2; ks++) {
            bf16x8 bfr[NI];
#pragma unroll
            for (int ni = 0; ni < NI; ni++)
                bfr[ni] = *(const bf16x8*)&lB[wc * (NI * 16) + ni * 16 + l15][(ks * 32 + quad * 8) ^ xo];
#pragma unroll
            for (int mi = 0; mi < MI; mi++) {
                bf16x8 afr = *(const bf16x8*)&lA[wr * (MI * 16) + mi * 16 + l15][(ks * 32 + quad * 8) ^ xo];
#pragma unroll
                for (int ni = 0; ni < NI; ni++)
                    acc[mi][ni] = __builtin_amdgcn_mfma_f32_16x16x32_bf16(afr, bfr[ni], acc[mi][ni], 0, 0, 0);
            }
        }
        __syncthreads();
    }

    float bias_v[NI];
#pragma unroll
    for (int ni = 0; ni < NI; ni++) bias_v[ni] = bias[n0 + wc * (NI * 16) + ni * 16 + l15];

#pragma unroll
    for (int mi = 0; mi < MI; mi++) {
#pragma unroll
        for (int r = 0; r < 4; r++) {
            int row = m0 + wr * (MI * 16) + mi * 16 + quad * 4 + r;
            size_t base = (size_t)row * N;
#pragma unroll
            for (int ni = 0; ni < NI; ni++) {
                int col = n0 + wc * (NI * 16) + ni * 16 + l15;
                float v = acc[mi][ni][r] + bias_v[ni];
                if (EPI == 2) v = 0.5f * v * (1.f + erff(v * 0.70710678118f));
                if (EPI == 1 || EPI == 3) v += ldf(res + base + col);
                stf(out + base + col, v);
            }
        }
    }
}

// =====================================================================
// Flash distance-attention v7: exp2-domain fold, MFMA rowsum.
// 512 threads / 8 waves per block; grid fixed at 512 blocks (2/CU), so
// 8 waves doubles resident waves/SIMD (2->4) at identical LDS footprint.
// Staging split: waves 0-3 build VbT (interleave), waves 4-7 stage KbT.
// =====================================================================
__global__ __launch_bounds__(512) void attn6_kernel(const USH* __restrict__ zq_pack,
                                                    const USH* __restrict__ zk_pack,
                                                    const USH* __restrict__ value,
                                                    USH* __restrict__ attn_out) {
    int b = blockIdx.x >> 4, h = blockIdx.x & 15;
    int q0 = blockIdx.y * 128;
    int tid = threadIdx.x, lane = tid & 63, wq = tid >> 6;   // wq 0..7
    int quad = lane >> 4, l15 = lane & 15;

    __shared__ __align__(16) USH Qb[128][40];
    __shared__ __align__(16) USH KbT[64][40];
    __shared__ __align__(16) USH VbT[64][72];
    __shared__ __align__(16) USH Pb[8][16][72];

    const size_t zrow0 = (size_t)b * 2048;
    const USH* zq = zq_pack + ((size_t)h * 4096 + zrow0) * 32;
    const USH* zk = zk_pack + ((size_t)h * 4096 + zrow0) * 32;
    const size_t vbase = zrow0 * 1024 + h * 64;

    {
        // 512 threads load 128 rows x 32 cols (8 USH each)
        int row = tid >> 2, c0 = (tid & 3) * 8;
        *(uint4*)&Qb[row][c0] = *(const uint4*)(zq + (size_t)(q0 + row) * 32 + c0);
    }
    __syncthreads();

    bf16x8 afragQ = *(const bf16x8*)&Qb[wq * 16 + l15][quad * 8];

    // ones fragment (bf16 1.0 x8)
    union { unsigned int u[4]; bf16x8 v; } onesu;
#pragma unroll
    for (int i = 0; i < 4; i++) onesu.u[i] = 0x3F803F80u;
    bf16x8 ones = onesu.v;

    floatx4 oacc[4] = {};
    floatx4 lacc = {};

    for (int kt = 0; kt < 2048; kt += 64) {
        __syncthreads();
        if (tid < 256) {
            // waves 0-3: VbT interleaved transpose (2 keys x 8 dh per thread)
            int key2 = (tid & 31) * 2;
            int dh0 = (tid >> 5) * 8;
            const USH* s0 = value + vbase + (size_t)(kt + key2) * 1024 + dh0;
            int4 ta = *(const int4*)s0;
            int4 tb = *(const int4*)(s0 + 1024);
            const USH* ua = (const USH*)&ta;
            const USH* ub = (const USH*)&tb;
#pragma unroll
            for (int e = 0; e < 8; e++) {
                unsigned int dw = (unsigned int)ua[e] | ((unsigned int)ub[e] << 16);
                *(unsigned int*)&VbT[dh0 + e][key2] = dw;
            }
        } else {
            // waves 4-7: KbT rows (16B per thread)
            int t = tid - 256;
            int row = t >> 2, c0 = (t & 3) * 8;
            *(uint4*)&KbT[row][c0] = *(const uint4*)(zk + (size_t)(kt + row) * 32 + c0);
        }
        __syncthreads();

        bf16x8 bk[4];
#pragma unroll
        for (int ni = 0; ni < 4; ni++)
            bk[ni] = *(const bf16x8*)&KbT[ni * 16 + l15][quad * 8];

        floatx4 sacc[4];
#pragma unroll
        for (int ni = 0; ni < 4; ni++) {
            floatx4 zz = {};
            sacc[ni] = __builtin_amdgcn_mfma_f32_16x16x32_bf16(afragQ, bk[ni], zz, 0, 0, 0);
        }
#pragma unroll
        for (int r = 0; r < 4; r++) {
#pragma unroll
            for (int ni = 0; ni < 4; ni++) {
                float pf = exp2f(sacc[ni][r]);   // single v_exp_f32
                union { float f; unsigned int i; } cv; cv.f = pf;
                Pb[wq][quad * 4 + r][ni * 16 + l15] = (USH)(cv.i >> 16);
            }
        }

        // ---- PV + rowsum (Pb wave-private; same-wave LDS in-order) ----
#pragma unroll
        for (int ks2 = 0; ks2 < 2; ks2++) {
            bf16x8 bv[4];
#pragma unroll
            for (int nd = 0; nd < 4; nd++)
                bv[nd] = *(const bf16x8*)&VbT[nd * 16 + l15][ks2 * 32 + quad * 8];
            bf16x8 ap = *(const bf16x8*)&Pb[wq][l15][ks2 * 32 + quad * 8];
#pragma unroll
            for (int nd = 0; nd < 4; nd++)
                oacc[nd] = __builtin_amdgcn_mfma_f32_16x16x32_bf16(ap, bv[nd], oacc[nd], 0, 0, 0);
            lacc = __builtin_amdgcn_mfma_f32_16x16x32_bf16(ap, ones, lacc, 0, 0, 0);
        }
    }

    // ---- epilogue: lacc holds the rowsum in every column ----
#pragma unroll
    for (int r = 0; r < 4; r++) {
        float inv = 1.f / lacc[r];
        int row = q0 + wq * 16 + quad * 4 + r;
        USH* o = attn_out + (zrow0 + row) * 1024 + h * 64;
#pragma unroll
        for (int nd = 0; nd < 4; nd++) o[nd * 16 + l15] = f2b(oacc[nd][r] * inv);
    }
}

// =====================================================================
// z_out = LN(z + z_next) over rows of 64. block = 64 (one wave) per row.
// =====================================================================
__global__ __launch_bounds__(64) void lnc_kernel(const float* __restrict__ z,
                                                 const float* __restrict__ zn,
                                                 const float* __restrict__ g,
                                                 const float* __restrict__ bb,
                                                 float* __restrict__ out) {
    int row = blockIdx.x, t = threadIdx.x;
    float v = z[(size_t)row * 64 + t] + zn[(size_t)row * 64 + t];
    float s = v, ss = v * v;
#pragma unroll
    for (int o = 32; o; o >>= 1) { s += __shfl_xor(s, o); ss += __shfl_xor(ss, o); }
    float mean = s * (1.f / 64.f);
    float rstd = rsqrtf(ss * (1.f / 64.f) - mean * mean + 1e-5f);
    out[(size_t)row * 64 + t] = (v - mean) * rstd * g[t] + bb[t];
}

// =====================================================================
extern "C" void kernel_launch(void* const* d_in, const int* in_sizes, int n_in,
                              void* d_out, int out_size, void* d_ws, size_t ws_size,
                              hipStream_t stream) {
    // workspace layout (61 MB):
    //   [0,8M)    value    [8,16M) attn_o    [16,20M) zq_pack
    //   [20,24M)  zk_pack  [24,32M) hn
    //   [0,32M)   mid (overlays, written step 8)
    //   [32,40M)  hn2   [40,41M) znext
    //   [41,43M)  wvT  [43,45M) woT  [45,53M) w1T  [53,61M) w2T
    //   wcnT (128K, bf16 [64][1024]) borrows the head of the attn_o
    //   region: written step 0, read step 4, overwritten step 5.
    // h1 (f32) lives in d_out's h region.
    char* p = (char*)d_ws;
    USH*   value   = (USH*)(p);
    USH*   attn_o  = (USH*)(p + ((size_t)8  << 20));
    USH*   wcnT    = (USH*)(p + ((size_t)8  << 20));   // overlay, pre-step-5
    USH*   zq_pack = (USH*)(p + ((size_t)16 << 20));
    USH*   zk_pack = (USH*)(p + ((size_t)20 << 20));
    USH*   hn      = (USH*)(p + ((size_t)24 << 20));
    USH*   mid     = (USH*)(p);
    USH*   hn2     = (USH*)(p + ((size_t)32 << 20));
    float* znext   = (float*)(p + ((size_t)40 << 20));
    USH*   wvT     = (USH*)(p + ((size_t)41 << 20));
    USH*   woT     = (USH*)(p + ((size_t)43 << 20));
    USH*   w1T     = (USH*)(p + ((size_t)45 << 20));
    USH*   w2T     = (USH*)(p + ((size_t)53 << 20));

    const float *h    = (const float*)d_in[0],  *z    = (const float*)d_in[1];
    const float *wv   = (const float*)d_in[2],  *bv   = (const float*)d_in[3];
    const float *wca  = (const float*)d_in[4],  *bca  = (const float*)d_in[5];
    const float *wcn  = (const float*)d_in[6],  *bcn  = (const float*)d_in[7];
    const float *wo   = (const float*)d_in[8],  *bo   = (const float*)d_in[9];
    const float *gam  = (const float*)d_in[10];
    const float *w1   = (const float*)d_in[11], *b1   = (const float*)d_in[12];
    const float *w2   = (const float*)d_in[13], *b2   = (const float*)d_in[14];
    const float *ln1g = (const float*)d_in[15], *ln1b = (const float*)d_in[16];
    const float *ln2g = (const float*)d_in[17], *ln2b = (const float*)d_in[18];
    const float *lncg = (const float*)d_in[19], *lncb = (const float*)d_in[20];

    float* out_h = (float*)d_out;
    float* out_z = out_h + (size_t)4096 * 1024;
    float* h1    = out_h;

    // 0. weight conversion (f32 [K][N] -> bf16 [N][K])
    transpose_f2b<<<dim3(16, 16), 256, 0, stream>>>(wv, wvT, 1024, 1024);
    transpose_f2b<<<dim3(16, 16), 256, 0, stream>>>(wo, woT, 1024, 1024);
    transpose_f2b<<<dim3(64, 16), 256, 0, stream>>>(w1, w1T, 1024, 4096);
    transpose_f2b<<<dim3(16, 64), 256, 0, stream>>>(w2, w2T, 4096, 1024);
    transpose_f2b<<<dim3(1, 16),  256, 0, stream>>>(wcn, wcnT, 1024, 64);

    // 1. hn = LN1(h)
    ln_rows<float><<<4096, 256, 0, stream>>>(h, ln1g, ln1b, hn);
    // 2. packed attention operands from z (exp2-domain)
    zh_kernel<<<4096, 256, 0, stream>>>(z, wca, bca, gam, zq_pack, zk_pack);
    // 3. value = hn @ wv + bv           (64x64 tiles, 1024 blocks)
    gemm_kernel<0, 2, 2, USH, USH><<<dim3(64, 16), 256, 0, stream>>>(hn, wvT, bv, (const USH*)nullptr, value, 4096, 1024, 1024);
    // 4. z_next = hn @ wcn + bcn        (MFMA, 32x32 tiles, 256 blocks)
    gemm_kernel<0, 1, 1, float, float><<<dim3(128, 2), 256, 0, stream>>>(hn, wcnT, bcn, (const float*)nullptr, znext, 4096, 64, 1024);
    // 5. attention (MFMA flash, exp2-fold, MFMA rowsum) — 512 thr / 8 waves
    attn6_kernel<<<dim3(32, 16), 512, 0, stream>>>(zq_pack, zk_pack, value, attn_o);
    // 6. h1 = h + attn_o @ wo + bo      (out f32 -> d_out h-region)
    gemm_kernel<1, 2, 2, float, float><<<dim3(64, 16), 256, 0, stream>>>(attn_o, woT, bo, h, h1, 4096, 1024, 1024);
    // 7. hn2 = LN2(h1)
    ln_rows<float><<<4096, 256, 0, stream>>>(h1, ln2g, ln2b, hn2);
    // 8. mid = gelu(hn2 @ w1 + b1)      (128x128 tiles, 1024 blocks)
    gemm_kernel<2, 4, 4, USH, USH><<<dim3(32, 32), 256, 0, stream>>>(hn2, w1T, b1, (const USH*)nullptr, mid, 4096, 4096, 1024);
    // 9. out_h = h1 + mid @ w2 + b2     (res==out same-thread, safe)
    gemm_kernel<3, 2, 2, float, float><<<dim3(64, 16), 256, 0, stream>>>(mid, w2T, b2, h1, out_h, 4096, 1024, 4096);
    // 10. out_z = LN(z + znext)
    lnc_kernel<<<4096, 64, 0, stream>>>(z, znext, lncg, lncb, out_z);
}

// Round 3
// 370.808 us; speedup vs baseline: 1.1981x; 1.0710x over previous
//
#include <hip/hip_runtime.h>

#define USH unsigned short

// ---------- bf16 helpers (storage = unsigned short) ----------
__device__ __forceinline__ float b2f(USH u) {
    union { unsigned int i; float f; } x; x.i = ((unsigned int)u) << 16; return x.f;
}
__device__ __forceinline__ USH f2b(float f) {
    union { float f; unsigned int i; } x; x.f = f;
    unsigned int r = x.i + (0x7fffu + ((x.i >> 16) & 1u));  // RNE
    return (USH)(r >> 16);
}
__device__ __forceinline__ float ldf(const USH* p)  { return b2f(*p); }
__device__ __forceinline__ float ldf(const float* p){ return *p; }
__device__ __forceinline__ void stf(USH* p, float v)  { *p = f2b(v); }
__device__ __forceinline__ void stf(float* p, float v){ *p = v; }

// async global->LDS, 16B per lane (dest = wave-uniform base + lane*16)
#define GLOAD16(gp, lp) __builtin_amdgcn_global_load_lds(                     \
    (const __attribute__((address_space(1))) void*)(gp),                      \
    (__attribute__((address_space(3))) void*)(lp), 16, 0, 0)

typedef __attribute__((ext_vector_type(8))) __bf16 bf16x8;
typedef __attribute__((ext_vector_type(4))) float  floatx4;

// =====================================================================
// Weight transpose+convert: W[K][N] f32 -> WT[N][K] bf16.
// =====================================================================
__global__ __launch_bounds__(256) void transpose_f2b(const float* __restrict__ W,
                                                     USH* __restrict__ WT,
                                                     int K, int N) {
    __shared__ USH t[64][72];
    int n0 = blockIdx.x * 64, k0 = blockIdx.y * 64;
    int tid = threadIdx.x;
    int kr = tid >> 4, nc = (tid & 15) * 4;
#pragma unroll
    for (int r = 0; r < 4; r++) {
        int k = kr + r * 16;
        float4 v = *(const float4*)(W + (size_t)(k0 + k) * N + n0 + nc);
        t[nc + 0][k] = f2b(v.x); t[nc + 1][k] = f2b(v.y);
        t[nc + 2][k] = f2b(v.z); t[nc + 3][k] = f2b(v.w);
    }
    __syncthreads();
    int nr = tid >> 2, kc = (tid & 3) * 8;
#pragma unroll
    for (int r = 0; r < 2; r++) {
        int k = kc + r * 32;
        *(int4*)(WT + (size_t)(n0 + nr) * K + k0 + k) = *(const int4*)&t[nr][k];
    }
}

// =====================================================================
// LayerNorm rows of 1024. block=256, one block/row.
// =====================================================================
template <typename TX>
__global__ __launch_bounds__(256) void ln_rows(const TX* __restrict__ x,
                                               const float* __restrict__ g,
                                               const float* __restrict__ bb,
                                               USH* __restrict__ y) {
    int row = blockIdx.x, tid = threadIdx.x;
    const TX* xr = x + (size_t)row * 1024 + tid * 4;
    float v[4];
#pragma unroll
    for (int i = 0; i < 4; i++) v[i] = ldf(xr + i);
    float s  = v[0] + v[1] + v[2] + v[3];
    float ss = v[0]*v[0] + v[1]*v[1] + v[2]*v[2] + v[3]*v[3];
#pragma unroll
    for (int o = 32; o; o >>= 1) { s += __shfl_down(s, o); ss += __shfl_down(ss, o); }
    __shared__ float red[10];
    int w = tid >> 6;
    if ((tid & 63) == 0) { red[w] = s; red[4 + w] = ss; }
    __syncthreads();
    if (tid == 0) {
        float S = red[0] + red[1] + red[2] + red[3];
        float SS = red[4] + red[5] + red[6] + red[7];
        float mean = S * (1.f / 1024.f);
        float var  = SS * (1.f / 1024.f) - mean * mean;
        red[8] = mean; red[9] = rsqrtf(var + 1e-5f);
    }
    __syncthreads();
    float mean = red[8], rstd = red[9];
    USH* yr = y + (size_t)row * 1024 + tid * 4;
#pragma unroll
    for (int i = 0; i < 4; i++) {
        int c = tid * 4 + i;
        yr[i] = f2b((v[i] - mean) * rstd * g[c] + bb[c]);
    }
}

// =====================================================================
// zh = z @ wca + bca, emitting packed MFMA operand rows (head-major),
// exp2-domain fold (gvl = softplus(gamma)*log2e):
//  zq_pack[h][row][32]: [ 2*gvl*s (16)], [16]=-gvl*ks, [17]=[18]=-gvl, 0..
//  zk_pack[h][row][32]: [ f2b(s) (16)],  [16]=1.0, [17]=ks_hi, [18]=ks_lo, 0..
// so mfma(zq_row, zk_row) = -gvl*(qs + ks - 2 q.k) <= 0 (log2 units),
// and p = exp2(sacc) is a single v_exp_f32.
// =====================================================================
__global__ __launch_bounds__(256) void zh_kernel(const float* __restrict__ z,
                                                 const float* __restrict__ wca,
                                                 const float* __restrict__ bca,
                                                 const float* __restrict__ gamma,
                                                 USH* __restrict__ zq_pack,
                                                 USH* __restrict__ zk_pack) {
    int row = blockIdx.x, n = threadIdx.x;
    __shared__ float zrow[64];
    if (n < 64) zrow[n] = z[(size_t)row * 64 + n];
    __syncthreads();
    float s = bca[n];
#pragma unroll 8
    for (int k = 0; k < 64; k++) s = fmaf(zrow[k], wca[(size_t)k * 256 + n], s);
    int h = n >> 4, c = n & 15;
    float gvl = log1pf(__expf(gamma[h])) * 1.44269504f;  // softplus * log2e
    USH u = f2b(s);
    float sv = b2f(u);
    float sq = sv * sv;
    sq += __shfl_xor(sq, 1); sq += __shfl_xor(sq, 2);
    sq += __shfl_xor(sq, 4); sq += __shfl_xor(sq, 8);
    size_t base = ((size_t)h * 4096 + row) * 32;
    zk_pack[base + c] = u;
    zq_pack[base + c] = f2b(2.f * gvl * s);
    if (c == 0) {
        USH hi = f2b(sq);
        float lo = sq - b2f(hi);
        unsigned int kw0 = 0x3F80u | ((unsigned int)hi << 16);
        unsigned int kw1 = (unsigned int)f2b(lo);
        uint4 kv = {kw0, kw1, 0u, 0u};
        uint4 zz = {0u, 0u, 0u, 0u};
        *(uint4*)(zk_pack + base + 16) = kv;
        *(uint4*)(zk_pack + base + 24) = zz;
        unsigned int qw0 = (unsigned int)f2b(-gvl * sq) | ((unsigned int)f2b(-gvl) << 16);
        unsigned int qw1 = (unsigned int)f2b(-gvl);
        uint4 qv = {qw0, qw1, 0u, 0u};
        *(uint4*)(zq_pack + base + 16) = qv;
        *(uint4*)(zq_pack + base + 24) = zz;
    }
}

// =====================================================================
// MFMA GEMM v5: BK=64, XOR-swizzled global_load_lds staging.
// Tile (MI*32) x (NI*32); 4 waves in 2x2.
// MI=NI=4 -> 128x128 tile, 32KB LDS (FFN1).
// MI=4,NI=2 -> 128x64 tile, 24KB LDS (N=1024 GEMMs: 16 MFMA / 6 loads
//   per K-step vs 8/4 at 64x64 -- tile ladder says 64x64 caps ~343 TF).
// MI=NI=1 -> 32x32 tile (skinny z_next GEMM, N=64).
// EPI: 0 = plain | 1 = +res | 2 = gelu | 3 = +res
// gelu = tanh-form (exp2+rcp, ~8 VALU ops) instead of erff (~30+):
// the erff epilogue was ~half of FFN1's VALUBusy at K=1024.
// =====================================================================
template <int EPI, int MI, int NI, typename TRES, typename TOUT>
__global__ __launch_bounds__(256) void gemm_kernel(const USH* __restrict__ A,
                                                   const USH* __restrict__ WT,
                                                   const float* __restrict__ bias,
                                                   const TRES* __restrict__ res,
                                                   TOUT* __restrict__ out,
                                                   int M, int N, int K) {
    constexpr int BM = MI * 32;
    constexpr int BN = NI * 32;
    __shared__ __align__(16) USH lA[BM][64];
    __shared__ __align__(16) USH lB[BN][64];
    int tid = threadIdx.x;
    int lane = tid & 63, wave = tid >> 6;
    int wr = wave >> 1, wc = wave & 1;
    int quad = lane >> 4, l15 = lane & 15;
    int m0 = blockIdx.x * BM, n0 = blockIdx.y * BN;

    int srow = tid >> 3;                 // 0..31 (rows per 4KB chunk)
    int k8   = tid & 7;                  // 16B granule within row
    int scol = (k8 ^ (srow & 7)) * 8;    // swizzled source column

    const USH* gA = A + (size_t)(m0 + srow) * K + scol;
    const USH* gB = WT + (size_t)(n0 + srow) * K + scol;
    USH* lA0 = &lA[0][0] + tid * 8;      // lane*16B dest
    USH* lB0 = &lB[0][0] + tid * 8;
    int xo = (l15 & 7) * 8;              // read-side XOR

    floatx4 acc[MI][NI] = {};

    for (int k0 = 0; k0 < K; k0 += 64) {
#pragma unroll
        for (int c = 0; c < MI; c++)
            GLOAD16(gA + (size_t)c * 32 * K + k0, lA0 + c * 2048);
#pragma unroll
        for (int c = 0; c < NI; c++)
            GLOAD16(gB + (size_t)c * 32 * K + k0, lB0 + c * 2048);
        __syncthreads();

#pragma unroll
        for (int ks = 0; ks < 2; ks++) {
            bf16x8 bfr[NI];
#pragma unroll
            for (int ni = 0; ni < NI; ni++)
                bfr[ni] = *(const bf16x8*)&lB[wc * (NI * 16) + ni * 16 + l15][(ks * 32 + quad * 8) ^ xo];
#pragma unroll
            for (int mi = 0; mi < MI; mi++) {
                bf16x8 afr = *(const bf16x8*)&lA[wr * (MI * 16) + mi * 16 + l15][(ks * 32 + quad * 8) ^ xo];
#pragma unroll
                for (int ni = 0; ni < NI; ni++)
                    acc[mi][ni] = __builtin_amdgcn_mfma_f32_16x16x32_bf16(afr, bfr[ni], acc[mi][ni], 0, 0, 0);
            }
        }
        __syncthreads();
    }

    float bias_v[NI];
#pragma unroll
    for (int ni = 0; ni < NI; ni++) bias_v[ni] = bias[n0 + wc * (NI * 16) + ni * 16 + l15];

#pragma unroll
    for (int mi = 0; mi < MI; mi++) {
#pragma unroll
        for (int r = 0; r < 4; r++) {
            int row = m0 + wr * (MI * 16) + mi * 16 + quad * 4 + r;
            size_t base = (size_t)row * N;
#pragma unroll
            for (int ni = 0; ni < NI; ni++) {
                int col = n0 + wc * (NI * 16) + ni * 16 + l15;
                float v = acc[mi][ni][r] + bias_v[ni];
                if (EPI == 2) {
                    // tanh-form GELU: v * sigmoid(1.5958*v + 0.07135*v^3)
                    float t = v * v;
                    float a = fmaf(t, -0.0713548162726f, -1.59576912161f);
                    v = v * __builtin_amdgcn_rcpf(1.f + __expf(v * a));
                }
                if (EPI == 1 || EPI == 3) v += ldf(res + base + col);
                stf(out + base + col, v);
            }
        }
    }
}

// =====================================================================
// Flash distance-attention v7: exp2-domain fold, MFMA rowsum.
// 512 threads / 8 waves per block; grid fixed at 512 blocks (2/CU), so
// 8 waves doubles resident waves/SIMD (2->4) at identical LDS footprint.
// Staging split: waves 0-3 build VbT (interleave), waves 4-7 stage KbT.
// =====================================================================
__global__ __launch_bounds__(512) void attn6_kernel(const USH* __restrict__ zq_pack,
                                                    const USH* __restrict__ zk_pack,
                                                    const USH* __restrict__ value,
                                                    USH* __restrict__ attn_out) {
    int b = blockIdx.x >> 4, h = blockIdx.x & 15;
    int q0 = blockIdx.y * 128;
    int tid = threadIdx.x, lane = tid & 63, wq = tid >> 6;   // wq 0..7
    int quad = lane >> 4, l15 = lane & 15;

    __shared__ __align__(16) USH Qb[128][40];
    __shared__ __align__(16) USH KbT[64][40];
    __shared__ __align__(16) USH VbT[64][72];
    __shared__ __align__(16) USH Pb[8][16][72];

    const size_t zrow0 = (size_t)b * 2048;
    const USH* zq = zq_pack + ((size_t)h * 4096 + zrow0) * 32;
    const USH* zk = zk_pack + ((size_t)h * 4096 + zrow0) * 32;
    const size_t vbase = zrow0 * 1024 + h * 64;

    {
        // 512 threads load 128 rows x 32 cols (8 USH each)
        int row = tid >> 2, c0 = (tid & 3) * 8;
        *(uint4*)&Qb[row][c0] = *(const uint4*)(zq + (size_t)(q0 + row) * 32 + c0);
    }
    __syncthreads();

    bf16x8 afragQ = *(const bf16x8*)&Qb[wq * 16 + l15][quad * 8];

    // ones fragment (bf16 1.0 x8)
    union { unsigned int u[4]; bf16x8 v; } onesu;
#pragma unroll
    for (int i = 0; i < 4; i++) onesu.u[i] = 0x3F803F80u;
    bf16x8 ones = onesu.v;

    floatx4 oacc[4] = {};
    floatx4 lacc = {};

    for (int kt = 0; kt < 2048; kt += 64) {
        __syncthreads();
        if (tid < 256) {
            // waves 0-3: VbT interleaved transpose (2 keys x 8 dh per thread)
            int key2 = (tid & 31) * 2;
            int dh0 = (tid >> 5) * 8;
            const USH* s0 = value + vbase + (size_t)(kt + key2) * 1024 + dh0;
            int4 ta = *(const int4*)s0;
            int4 tb = *(const int4*)(s0 + 1024);
            const USH* ua = (const USH*)&ta;
            const USH* ub = (const USH*)&tb;
#pragma unroll
            for (int e = 0; e < 8; e++) {
                unsigned int dw = (unsigned int)ua[e] | ((unsigned int)ub[e] << 16);
                *(unsigned int*)&VbT[dh0 + e][key2] = dw;
            }
        } else {
            // waves 4-7: KbT rows (16B per thread)
            int t = tid - 256;
            int row = t >> 2, c0 = (t & 3) * 8;
            *(uint4*)&KbT[row][c0] = *(const uint4*)(zk + (size_t)(kt + row) * 32 + c0);
        }
        __syncthreads();

        bf16x8 bk[4];
#pragma unroll
        for (int ni = 0; ni < 4; ni++)
            bk[ni] = *(const bf16x8*)&KbT[ni * 16 + l15][quad * 8];

        floatx4 sacc[4];
#pragma unroll
        for (int ni = 0; ni < 4; ni++) {
            floatx4 zz = {};
            sacc[ni] = __builtin_amdgcn_mfma_f32_16x16x32_bf16(afragQ, bk[ni], zz, 0, 0, 0);
        }
#pragma unroll
        for (int r = 0; r < 4; r++) {
#pragma unroll
            for (int ni = 0; ni < 4; ni++) {
                float pf = exp2f(sacc[ni][r]);   // single v_exp_f32
                union { float f; unsigned int i; } cv; cv.f = pf;
                Pb[wq][quad * 4 + r][ni * 16 + l15] = (USH)(cv.i >> 16);
            }
        }

        // ---- PV + rowsum (Pb wave-private; same-wave LDS in-order) ----
#pragma unroll
        for (int ks2 = 0; ks2 < 2; ks2++) {
            bf16x8 bv[4];
#pragma unroll
            for (int nd = 0; nd < 4; nd++)
                bv[nd] = *(const bf16x8*)&VbT[nd * 16 + l15][ks2 * 32 + quad * 8];
            bf16x8 ap = *(const bf16x8*)&Pb[wq][l15][ks2 * 32 + quad * 8];
#pragma unroll
            for (int nd = 0; nd < 4; nd++)
                oacc[nd] = __builtin_amdgcn_mfma_f32_16x16x32_bf16(ap, bv[nd], oacc[nd], 0, 0, 0);
            lacc = __builtin_amdgcn_mfma_f32_16x16x32_bf16(ap, ones, lacc, 0, 0, 0);
        }
    }

    // ---- epilogue: lacc holds the rowsum in every column ----
#pragma unroll
    for (int r = 0; r < 4; r++) {
        float inv = 1.f / lacc[r];
        int row = q0 + wq * 16 + quad * 4 + r;
        USH* o = attn_out + (zrow0 + row) * 1024 + h * 64;
#pragma unroll
        for (int nd = 0; nd < 4; nd++) o[nd * 16 + l15] = f2b(oacc[nd][r] * inv);
    }
}

// =====================================================================
// z_out = LN(z + z_next) over rows of 64. block = 64 (one wave) per row.
// =====================================================================
__global__ __launch_bounds__(64) void lnc_kernel(const float* __restrict__ z,
                                                 const float* __restrict__ zn,
                                                 const float* __restrict__ g,
                                                 const float* __restrict__ bb,
                                                 float* __restrict__ out) {
    int row = blockIdx.x, t = threadIdx.x;
    float v = z[(size_t)row * 64 + t] + zn[(size_t)row * 64 + t];
    float s = v, ss = v * v;
#pragma unroll
    for (int o = 32; o; o >>= 1) { s += __shfl_xor(s, o); ss += __shfl_xor(ss, o); }
    float mean = s * (1.f / 64.f);
    float rstd = rsqrtf(ss * (1.f / 64.f) - mean * mean + 1e-5f);
    out[(size_t)row * 64 + t] = (v - mean) * rstd * g[t] + bb[t];
}

// =====================================================================
extern "C" void kernel_launch(void* const* d_in, const int* in_sizes, int n_in,
                              void* d_out, int out_size, void* d_ws, size_t ws_size,
                              hipStream_t stream) {
    // workspace layout (61 MB):
    //   [0,8M)    value    [8,16M) attn_o    [16,20M) zq_pack
    //   [20,24M)  zk_pack  [24,32M) hn
    //   [0,32M)   mid (overlays, written step 8)
    //   [32,40M)  hn2   [40,41M) znext
    //   [41,43M)  wvT  [43,45M) woT  [45,53M) w1T  [53,61M) w2T
    //   wcnT (128K, bf16 [64][1024]) borrows the head of the attn_o
    //   region: written step 0, read step 4, overwritten step 5.
    // h1 (f32) lives in d_out's h region.
    char* p = (char*)d_ws;
    USH*   value   = (USH*)(p);
    USH*   attn_o  = (USH*)(p + ((size_t)8  << 20));
    USH*   wcnT    = (USH*)(p + ((size_t)8  << 20));   // overlay, pre-step-5
    USH*   zq_pack = (USH*)(p + ((size_t)16 << 20));
    USH*   zk_pack = (USH*)(p + ((size_t)20 << 20));
    USH*   hn      = (USH*)(p + ((size_t)24 << 20));
    USH*   mid     = (USH*)(p);
    USH*   hn2     = (USH*)(p + ((size_t)32 << 20));
    float* znext   = (float*)(p + ((size_t)40 << 20));
    USH*   wvT     = (USH*)(p + ((size_t)41 << 20));
    USH*   woT     = (USH*)(p + ((size_t)43 << 20));
    USH*   w1T     = (USH*)(p + ((size_t)45 << 20));
    USH*   w2T     = (USH*)(p + ((size_t)53 << 20));

    const float *h    = (const float*)d_in[0],  *z    = (const float*)d_in[1];
    const float *wv   = (const float*)d_in[2],  *bv   = (const float*)d_in[3];
    const float *wca  = (const float*)d_in[4],  *bca  = (const float*)d_in[5];
    const float *wcn  = (const float*)d_in[6],  *bcn  = (const float*)d_in[7];
    const float *wo   = (const float*)d_in[8],  *bo   = (const float*)d_in[9];
    const float *gam  = (const float*)d_in[10];
    const float *w1   = (const float*)d_in[11], *b1   = (const float*)d_in[12];
    const float *w2   = (const float*)d_in[13], *b2   = (const float*)d_in[14];
    const float *ln1g = (const float*)d_in[15], *ln1b = (const float*)d_in[16];
    const float *ln2g = (const float*)d_in[17], *ln2b = (const float*)d_in[18];
    const float *lncg = (const float*)d_in[19], *lncb = (const float*)d_in[20];

    float* out_h = (float*)d_out;
    float* out_z = out_h + (size_t)4096 * 1024;
    float* h1    = out_h;

    // 0. weight conversion (f32 [K][N] -> bf16 [N][K])
    transpose_f2b<<<dim3(16, 16), 256, 0, stream>>>(wv, wvT, 1024, 1024);
    transpose_f2b<<<dim3(16, 16), 256, 0, stream>>>(wo, woT, 1024, 1024);
    transpose_f2b<<<dim3(64, 16), 256, 0, stream>>>(w1, w1T, 1024, 4096);
    transpose_f2b<<<dim3(16, 64), 256, 0, stream>>>(w2, w2T, 4096, 1024);
    transpose_f2b<<<dim3(1, 16),  256, 0, stream>>>(wcn, wcnT, 1024, 64);

    // 1. hn = LN1(h)
    ln_rows<float><<<4096, 256, 0, stream>>>(h, ln1g, ln1b, hn);
    // 2. packed attention operands from z (exp2-domain)
    zh_kernel<<<4096, 256, 0, stream>>>(z, wca, bca, gam, zq_pack, zk_pack);
    // 3. value = hn @ wv + bv           (128x64 tiles, 512 blocks)
    gemm_kernel<0, 4, 2, USH, USH><<<dim3(32, 16), 256, 0, stream>>>(hn, wvT, bv, (const USH*)nullptr, value, 4096, 1024, 1024);
    // 4. z_next = hn @ wcn + bcn        (MFMA, 32x32 tiles, 256 blocks)
    gemm_kernel<0, 1, 1, float, float><<<dim3(128, 2), 256, 0, stream>>>(hn, wcnT, bcn, (const float*)nullptr, znext, 4096, 64, 1024);
    // 5. attention (MFMA flash, exp2-fold, MFMA rowsum) — 512 thr / 8 waves
    attn6_kernel<<<dim3(32, 16), 512, 0, stream>>>(zq_pack, zk_pack, value, attn_o);
    // 6. h1 = h + attn_o @ wo + bo      (128x64 tiles, out f32 -> d_out)
    gemm_kernel<1, 4, 2, float, float><<<dim3(32, 16), 256, 0, stream>>>(attn_o, woT, bo, h, h1, 4096, 1024, 1024);
    // 7. hn2 = LN2(h1)
    ln_rows<float><<<4096, 256, 0, stream>>>(h1, ln2g, ln2b, hn2);
    // 8. mid = gelu(hn2 @ w1 + b1)      (128x128 tiles, 1024 blocks)
    gemm_kernel<2, 4, 4, USH, USH><<<dim3(32, 32), 256, 0, stream>>>(hn2, w1T, b1, (const USH*)nullptr, mid, 4096, 4096, 1024);
    // 9. out_h = h1 + mid @ w2 + b2     (128x64 tiles, res==out same-thread)
    gemm_kernel<3, 4, 2, float, float><<<dim3(32, 16), 256, 0, stream>>>(mid, w2T, b2, h1, out_h, 4096, 1024, 4096);
    // 10. out_z = LN(z + znext)
    lnc_kernel<<<4096, 64, 0, stream>>>(z, znext, lncg, lncb, out_z);
}